// Round 1
// baseline (80135.370 us; speedup 1.0000x reference)
//
#include <hip/hip_runtime.h>
#include <hip/hip_cooperative_groups.h>
#include <math.h>

namespace cg = cooperative_groups;

// Problem constants
#define Bb    64
#define Ss    1024
#define CINc  256
#define Hh    512
#define Kk    768          // CIN + H
#define NBLK  256          // one block per CU; each owns 2 hidden units
#define NTHR  256          // 4 waves
#define CHUNK 192          // k-chunk staged in LDS
#define NCHUNK 4           // 768 / 192
#define SLOTS 8            // 4 gates x 2 units

// ws layout: [wt: NBLK*SLOTS*Kk floats][hbuf: 2*Bb*Hh floats]
#define WT_FLOATS   (NBLK * SLOTS * Kk)
#define HBUF_FLOATS (2 * Bb * Hh)

// Extract center-tap weights into block-major layout:
// wt[bl][s][k] = W[(col*Kk + k)*3 + 1], col = 2*bl + (s&1) + Hh*(s>>1)
__global__ void extract_weights(const float* __restrict__ W, float* __restrict__ wt) {
    int total = WT_FLOATS;
    for (int idx = blockIdx.x * blockDim.x + threadIdx.x; idx < total;
         idx += gridDim.x * blockDim.x) {
        int k    = idx % Kk;
        int rest = idx / Kk;
        int s    = rest % SLOTS;
        int bl   = rest / SLOTS;
        int col  = 2 * bl + (s & 1) + Hh * (s >> 1);
        wt[idx] = W[((size_t)col * Kk + k) * 3 + 1];
    }
}

__device__ __forceinline__ float sigf(float v) { return 1.0f / (1.0f + expf(-v)); }

__global__ __launch_bounds__(NTHR, 1) void lstm_coop(
    const float* __restrict__ x,    // [B,S,CIN]
    const float* __restrict__ bias, // [4H]
    const float* __restrict__ h0,   // [B,H]
    const float* __restrict__ c0,   // [B,H]
    const float* __restrict__ wt,   // [NBLK][SLOTS][Kk]
    float* __restrict__ hbuf,       // [2][B][H]
    float* __restrict__ out)        // [B,S,H] ++ [B,H] ++ [B,H]
{
    __shared__ float a_lds[CHUNK][Bb];   // 48 KB: combined[k][b] chunk
    __shared__ float g_lds[SLOTS][Bb];   // 2 KB: gate values

    cg::grid_group grid = cg::this_grid();

    const int tid  = threadIdx.x;
    const int lane = tid & 63;                                   // b for compute
    const int q    = __builtin_amdgcn_readfirstlane(tid >> 6);   // wave id 0..3
    const int bl   = blockIdx.x;
    const int u0   = 2 * bl;

    // Weight rows for slots q and q+4 (scalar-load friendly: uniform address)
    const float* w0 = wt + ((size_t)bl * SLOTS + q) * Kk;
    const float* w1 = w0 + 4 * (size_t)Kk;

    // col(s) = u0 + (s&1) + Hh*(s>>1);  slot q+4 is col(q) + 2*Hh
    const int  colA  = u0 + (q & 1) + Hh * (q >> 1);
    const float biasA = bias[colA];
    const float biasB = bias[colA + 2 * Hh];

    // init hbuf[0] from h0 (grid-wide cooperative copy)
    for (int i = bl * NTHR + tid; i < Bb * Hh; i += NBLK * NTHR) hbuf[i] = h0[i];

    // cell state for updater threads (waves 0,1): cell (b=lane, u = u0+q)
    float cstate = 0.f;
    int   ucell  = 0;
    if (q < 2) {
        ucell  = u0 + q;
        cstate = c0[(size_t)lane * Hh + ucell];
    }

    __threadfence();
    grid.sync();

    // staging mapping: 4 threads per row, row bb = tid>>2
    const int bb  = tid >> 2;
    const int sub = tid & 3;
    const float* xrow_base = x + (size_t)bb * Ss * CINc;

    for (int t = 0; t < Ss; ++t) {
        const int cur = t & 1;
        const float* hsrc = hbuf + (size_t)cur * Bb * Hh;
        const float* xrow = xrow_base + (size_t)t * CINc;
        const float* hrow = hsrc + (size_t)bb * Hh;

        float accA = biasA;
        float accB = biasB;

        for (int ch = 0; ch < NCHUNK; ++ch) {
            __syncthreads();   // a_lds reuse safe
            // stage chunk: k in [ch*CHUNK, (ch+1)*CHUNK), 48 floats per thread
            #pragma unroll
            for (int j = 0; j < CHUNK / 16; ++j) {     // 12 float4 per thread
                int f     = sub + 4 * j;               // float4 index within chunk
                int kloc  = 4 * f;
                int kglob = ch * CHUNK + kloc;
                const float* srcp = (kglob < CINc) ? (xrow + kglob)
                                                   : (hrow + (kglob - CINc));
                float4 v = *(const float4*)srcp;
                a_lds[kloc + 0][bb] = v.x;
                a_lds[kloc + 1][bb] = v.y;
                a_lds[kloc + 2][bb] = v.z;
                a_lds[kloc + 3][bb] = v.w;
            }
            __syncthreads();

            const int kbase = ch * CHUNK;
            #pragma unroll 4
            for (int kk = 0; kk < CHUNK; kk += 4) {
                float4 wa = *(const float4*)(w0 + kbase + kk);
                float4 wb = *(const float4*)(w1 + kbase + kk);
                float a0 = a_lds[kk + 0][lane];
                float a1 = a_lds[kk + 1][lane];
                float a2 = a_lds[kk + 2][lane];
                float a3 = a_lds[kk + 3][lane];
                accA = fmaf(a0, wa.x, accA);
                accA = fmaf(a1, wa.y, accA);
                accA = fmaf(a2, wa.z, accA);
                accA = fmaf(a3, wa.w, accA);
                accB = fmaf(a0, wb.x, accB);
                accB = fmaf(a1, wb.y, accB);
                accB = fmaf(a2, wb.z, accB);
                accB = fmaf(a3, wb.w, accB);
            }
        }

        // publish gates to LDS: slot q and q+4
        g_lds[q][lane]     = accA;
        g_lds[q + 4][lane] = accB;
        __syncthreads();

        // cell update: waves 0,1 handle units u0+0, u0+1 for b = lane
        if (q < 2) {
            float iv = sigf(g_lds[0 + q][lane]);
            float fv = sigf(g_lds[2 + q][lane]);
            float gv = tanhf(g_lds[4 + q][lane]);
            float ov = sigf(g_lds[6 + q][lane]);
            cstate = fv * cstate + iv * gv;
            float hv = ov * tanhf(cstate);
            hbuf[(size_t)(cur ^ 1) * Bb * Hh + (size_t)lane * Hh + ucell] = hv;
            out[((size_t)lane * Ss + t) * Hh + ucell] = hv;
            if (t == Ss - 1) {
                // final h and c outputs
                out[(size_t)Bb * Ss * Hh + (size_t)lane * Hh + ucell] = hv;
                out[(size_t)Bb * Ss * Hh + (size_t)Bb * Hh + (size_t)lane * Hh + ucell] = cstate;
            }
        }

        __threadfence();
        grid.sync();
    }
}

extern "C" void kernel_launch(void* const* d_in, const int* in_sizes, int n_in,
                              void* d_out, int out_size, void* d_ws, size_t ws_size,
                              hipStream_t stream) {
    const float* x    = (const float*)d_in[0];
    const float* W    = (const float*)d_in[1];
    const float* bias = (const float*)d_in[2];
    const float* h0   = (const float*)d_in[3];
    const float* c0   = (const float*)d_in[4];
    float* out = (float*)d_out;

    float* wt   = (float*)d_ws;                 // 6,291,456 B
    float* hbuf = wt + WT_FLOATS;               // 262,144 B

    extract_weights<<<256, 256, 0, stream>>>(W, wt);

    void* args[] = { (void*)&x, (void*)&bias, (void*)&h0, (void*)&c0,
                     (void*)&wt, (void*)&hbuf, (void*)&out };
    hipLaunchCooperativeKernel((const void*)lstm_coop, dim3(NBLK), dim3(NTHR),
                               args, 0, stream);
}

// Round 2
// 18589.117 us; speedup vs baseline: 4.3109x; 4.3109x over previous
//
#include <hip/hip_runtime.h>
#include <math.h>

// Problem constants
#define Bb    64
#define Ss    1024
#define CINc  256
#define Hh    512
#define Kk    768          // CIN + H
#define NBLK  256          // one block per CU; each owns 2 hidden units (8 gate rows)
#define NTHR  256          // 4 waves
#define CHUNK 128          // k-chunk staged in LDS (divides CIN=256 evenly: ch0,1 = x; ch2..5 = h)
#define NCHUNK 6
#define SLOTS 8            // 4 gates x 2 units

// ws layout: [wt: NBLK*SLOTS*Kk f32][hbuf: 2*B*H f32][ctr: 8 x 64B]
#define WT_FLOATS   (NBLK * SLOTS * Kk)
#define HBUF_FLOATS (2 * Bb * Hh)
#define NCTR 8
#define CTR_STRIDE 16      // uints -> 64 B apart (separate cache lines)

// Extract center-tap weights into block-major layout:
// wt[bl][s][k] = W[(col*Kk + k)*3 + 1], col = 2*bl + (s&1) + Hh*(s>>1)
__global__ void extract_weights(const float* __restrict__ W, float* __restrict__ wt) {
    int total = WT_FLOATS;
    for (int idx = blockIdx.x * blockDim.x + threadIdx.x; idx < total;
         idx += gridDim.x * blockDim.x) {
        int k    = idx % Kk;
        int rest = idx / Kk;
        int s    = rest % SLOTS;
        int bl   = rest / SLOTS;
        int col  = 2 * bl + (s & 1) + Hh * (s >> 1);
        wt[idx] = W[((size_t)col * Kk + k) * 3 + 1];
    }
}

__device__ __forceinline__ float sigf(float v) { return 1.0f / (1.0f + expf(-v)); }

// Explicit drain of my asm VMEM ops; "memory" clobber keeps LDS writes below it.
__device__ __forceinline__ void wait_vm0() {
    asm volatile("s_waitcnt vmcnt(0)" ::: "memory");
}
// LLC-coherent (bypass L1+L2) load/store for the h exchange. No fences needed:
// these always hit the coherence point, so L2 stays warm for W/x.
__device__ __forceinline__ float4 load4_llc(const float* p) {
    float4 v;
    asm volatile("global_load_dwordx4 %0, %1, off sc0 sc1" : "=&v"(v) : "v"(p) : "memory");
    return v;
}
__device__ __forceinline__ void store_llc(float* p, float v) {
    asm volatile("global_store_dword %0, %1, off sc0 sc1" :: "v"(p), "v"(v) : "memory");
}

__global__ __launch_bounds__(NTHR, 1) void lstm_coop(
    const float* __restrict__ x,    // [B,S,CIN]
    const float* __restrict__ bias, // [4H]
    const float* __restrict__ h0,   // [B,H]
    const float* __restrict__ c0,   // [B,H]
    const float* __restrict__ wt,   // [NBLK][SLOTS][Kk]
    float* __restrict__ hbuf,       // [2][B][H]  (LLC-coherent access only)
    unsigned* ctr,                  // 8 striped barrier counters
    float* __restrict__ out)        // [B,S,H] ++ [B,H] ++ [B,H]
{
    __shared__ float a_lds[CHUNK][Bb];     // 32 KB, XOR-swizzled in b
    __shared__ float w_lds[SLOTS * Kk];    // 24 KB, this block's 8 gate rows
    __shared__ float g_lds[SLOTS][Bb];     // 2 KB

    const int tid  = threadIdx.x;
    const int lane = tid & 63;
    const int q    = __builtin_amdgcn_readfirstlane(tid >> 6);  // wave 0..3
    const int bl   = blockIdx.x;
    const int u0   = 2 * bl;

    // ---- stage this block's weights into LDS once ----
    {
        const float4* wsrc = (const float4*)(wt + (size_t)bl * SLOTS * Kk);
        float4* wdst = (float4*)w_lds;
        for (int i = tid; i < SLOTS * Kk / 4; i += NTHR) wdst[i] = wsrc[i];
    }
    const float* w0 = w_lds + q * Kk;          // slot q   (i/f gates)
    const float* w1 = w_lds + (q + 4) * Kk;    // slot q+4 (g/o gates)

    const int   colA  = u0 + (q & 1) + Hh * (q >> 1);
    const float biasA = bias[colA];
    const float biasB = bias[colA + 2 * Hh];

    // ---- init hbuf[0] = h0 with LLC-coherent stores ----
    for (int i = bl * NTHR + tid; i < Bb * Hh; i += NBLK * NTHR) store_llc(&hbuf[i], h0[i]);
    wait_vm0();

    float cstate = 0.f;
    int   ucell  = 0;
    if (q < 2) {
        ucell  = u0 + q;
        cstate = c0[(size_t)lane * Hh + ucell];
    }

    __syncthreads();
    // ---- barrier phase 1 (init visible) ----
    if (tid == 0) __hip_atomic_fetch_add(&ctr[(bl & 7) * CTR_STRIDE], 1u,
                                         __ATOMIC_RELAXED, __HIP_MEMORY_SCOPE_AGENT);
    if (tid < NCTR) {
        while (__hip_atomic_load(&ctr[tid * CTR_STRIDE],
                                 __ATOMIC_RELAXED, __HIP_MEMORY_SCOPE_AGENT) < 32u)
            __builtin_amdgcn_s_sleep(2);
    }
    __atomic_signal_fence(__ATOMIC_SEQ_CST);
    __syncthreads();

    // staging mapping: 4 threads per batch row; bb = tid>>2, sub = tid&3
    const int bb  = tid >> 2;
    const int sub = tid & 3;
    const int bsw = bb ^ (sub << 4);   // swizzle: bank = f(k,b) conflict-free both sides

    const float* xrow_base = x + (size_t)bb * Ss * CINc + 4 * sub;

    for (int t = 0; t < Ss; ++t) {
        const int cur = t & 1;
        const float* hcur = hbuf + (size_t)cur * Bb * Hh;
        float*       hnxt = hbuf + (size_t)(cur ^ 1) * Bb * Hh;
        const float* xrow = xrow_base + (size_t)t * CINc;
        const float* hrow = hcur + (size_t)bb * Hh + 4 * sub;

        float accA = biasA;
        float accB = biasB;

        float4 v[8];
        // preload chunk 0 (x, normal cached loads; compiler handles waitcnt)
        #pragma unroll
        for (int j = 0; j < 8; ++j) v[j] = *(const float4*)(xrow + 16 * j);

        for (int ch = 0; ch < NCHUNK; ++ch) {
            __syncthreads();                 // a_lds reuse safe
            if (ch >= 2) wait_vm0();         // drain my asm h-loads before use
            #pragma unroll
            for (int j = 0; j < 8; ++j) {
                int kloc = 4 * (sub + 4 * j);
                a_lds[kloc + 0][bsw] = v[j].x;
                a_lds[kloc + 1][bsw] = v[j].y;
                a_lds[kloc + 2][bsw] = v[j].z;
                a_lds[kloc + 3][bsw] = v[j].w;
            }
            __syncthreads();

            // software pipeline: issue next chunk's global loads, overlap compute
            if (ch + 1 < NCHUNK) {
                if (ch + 1 < 2) {
                    const float* s0 = xrow + (ch + 1) * CHUNK;
                    #pragma unroll
                    for (int j = 0; j < 8; ++j) v[j] = *(const float4*)(s0 + 16 * j);
                } else {
                    const float* s0 = hrow + (ch - 1) * CHUNK;  // (ch+1-2)*CHUNK
                    #pragma unroll
                    for (int j = 0; j < 8; ++j) v[j] = load4_llc(s0 + 16 * j);
                }
            }

            const int kbase = ch * CHUNK;
            #pragma unroll 4
            for (int kk = 0; kk < CHUNK; kk += 4) {
                float4 wa = *(const float4*)(w0 + kbase + kk);   // LDS broadcast
                float4 wb = *(const float4*)(w1 + kbase + kk);
                const int bidx = lane ^ (((kk >> 2) & 3) << 4);
                float a0 = a_lds[kk + 0][bidx];
                float a1 = a_lds[kk + 1][bidx];
                float a2 = a_lds[kk + 2][bidx];
                float a3 = a_lds[kk + 3][bidx];
                accA = fmaf(a0, wa.x, accA);
                accA = fmaf(a1, wa.y, accA);
                accA = fmaf(a2, wa.z, accA);
                accA = fmaf(a3, wa.w, accA);
                accB = fmaf(a0, wb.x, accB);
                accB = fmaf(a1, wb.y, accB);
                accB = fmaf(a2, wb.z, accB);
                accB = fmaf(a3, wb.w, accB);
            }
        }

        g_lds[q][lane]     = accA;
        g_lds[q + 4][lane] = accB;
        __syncthreads();

        if (q < 2) {   // waves 0,1: cell update for units u0+q, b = lane
            float iv = sigf(g_lds[0 + q][lane]);
            float fv = sigf(g_lds[2 + q][lane]);
            float gv = tanhf(g_lds[4 + q][lane]);
            float ov = sigf(g_lds[6 + q][lane]);
            cstate = fv * cstate + iv * gv;
            float hv = ov * tanhf(cstate);
            store_llc(&hnxt[(size_t)lane * Hh + ucell], hv);   // coherent publish
            out[((size_t)lane * Ss + t) * Hh + ucell] = hv;
            if (t == Ss - 1) {
                out[(size_t)Bb * Ss * Hh + (size_t)lane * Hh + ucell] = hv;
                out[(size_t)Bb * Ss * Hh + (size_t)Bb * Hh + (size_t)lane * Hh + ucell] = cstate;
            }
        }
        wait_vm0();        // every thread drains its VMEM (h stores) before arrival
        __syncthreads();

        // ---- grid barrier, phase t+2: striped relaxed counters, no HW fences ----
        if (tid == 0) __hip_atomic_fetch_add(&ctr[(bl & 7) * CTR_STRIDE], 1u,
                                             __ATOMIC_RELAXED, __HIP_MEMORY_SCOPE_AGENT);
        const unsigned target = 32u * (unsigned)(t + 2);
        if (tid < NCTR) {
            while (__hip_atomic_load(&ctr[tid * CTR_STRIDE],
                                     __ATOMIC_RELAXED, __HIP_MEMORY_SCOPE_AGENT) < target)
                __builtin_amdgcn_s_sleep(2);
        }
        __atomic_signal_fence(__ATOMIC_SEQ_CST);
        __syncthreads();
        // Skew safety: a fast block's next write to the buffer this block just read
        // happens a full GEMM (~5K cyc) after the barrier opens; spin exit is ~1K cyc.
    }
}

extern "C" void kernel_launch(void* const* d_in, const int* in_sizes, int n_in,
                              void* d_out, int out_size, void* d_ws, size_t ws_size,
                              hipStream_t stream) {
    const float* x    = (const float*)d_in[0];
    const float* W    = (const float*)d_in[1];
    const float* bias = (const float*)d_in[2];
    const float* h0   = (const float*)d_in[3];
    const float* c0   = (const float*)d_in[4];
    float* out = (float*)d_out;

    float*    wt   = (float*)d_ws;
    float*    hbuf = wt + WT_FLOATS;
    unsigned* ctr  = (unsigned*)(hbuf + HBUF_FLOATS);

    hipMemsetAsync(ctr, 0, NCTR * CTR_STRIDE * sizeof(unsigned), stream);
    extract_weights<<<256, 256, 0, stream>>>(W, wt);

    void* args[] = { (void*)&x, (void*)&bias, (void*)&h0, (void*)&c0,
                     (void*)&wt, (void*)&hbuf, (void*)&ctr, (void*)&out };
    hipLaunchCooperativeKernel((const void*)lstm_coop, dim3(NBLK), dim3(NTHR),
                               args, 0, stream);
}